// Round 2
// baseline (136.452 us; speedup 1.0000x reference)
//
#include <hip/hip_runtime.h>

// MultiPositiveContrastiveLoss: B=32768 problems, C=64 candidates, P=16 pos, N=48 neg.
// v3: single fused kernel. v2's latency-restructured per-problem compute is kept
// bit-identical; the separate 1-block final kernel is replaced by a last-block-ticket
// reduction inside the same dispatch (removes one serialized graph node + launch gap).
// Ticket lives in workspace and is zeroed by a 4-byte hipMemsetAsync node (workspace is
// poison-filled by the harness each iteration, so it must be re-zeroed in-stream).
// Cross-XCD visibility: partials are written/read with agent-scope atomics (per-XCD L2s
// are not coherent; G16), ticket uses acq-rel agent-scope fetch_add.

#define MARGIN 0.5f

constexpr int C = 64;
constexpr int P = 16;
constexpr int N = 48;
constexpr int BLOCK = 256;
constexpr int WAVES_PER_BLOCK = BLOCK / 64;      // 4
constexpr int PROBS_PER_WAVE = 4;
constexpr int PROBS_PER_BLOCK = WAVES_PER_BLOCK * PROBS_PER_WAVE;  // 16

__device__ __forceinline__ float readlane_f(float v, int l) {
    return __uint_as_float(__builtin_amdgcn_readlane(__float_as_uint(v), l));
}

union pk64 { float2 f; unsigned long long u; };

__global__ __launch_bounds__(BLOCK) void mpcl_fused_kernel(
    const float* __restrict__ scores,
    const int*   __restrict__ pos_indices,
    const int*   __restrict__ neg_indices,
    const int*   __restrict__ pos_counts,
    const int*   __restrict__ neg_counts,
    unsigned long long* __restrict__ partials,   // packed float2, agent-scope
    unsigned*    __restrict__ ticket,            // zeroed by memset node
    float*       __restrict__ out,
    int B)
{
    const int lane = threadIdx.x & 63;
    const int wave = threadIdx.x >> 6;
    const int b0 = (blockIdx.x * WAVES_PER_BLOCK + wave) * PROBS_PER_WAVE;

    float tot = 0.0f;
    float cnt = 0.0f;

    if (b0 + PROBS_PER_WAVE <= B) {
        // ---- fast path: batch ALL loads, zero dependency levels between them ----
        int   pc[PROBS_PER_WAVE], nc[PROBS_PER_WAVE], idx[PROBS_PER_WAVE];
        float sc[PROBS_PER_WAVE];
        #pragma unroll
        for (int k = 0; k < PROBS_PER_WAVE; ++k) {
            const int b = b0 + k;
            pc[k] = pos_counts[b];                       // wave-uniform
            nc[k] = neg_counts[b];
            idx[k] = (lane >= 48)
                ? pos_indices[(size_t)b * P + (lane - 48)]
                : neg_indices[(size_t)b * N + lane];     // coalesced per arm
            sc[k] = scores[(size_t)b * C + lane];        // fully coalesced: C == 64
        }

        #pragma unroll
        for (int k = 0; k < PROBS_PER_WAVE; ++k) {
            // in-wave gather: candidate idx in [0,64) -> ds_bpermute
            const float val  = __shfl(sc[k], idx[k]);
            // lanes >= 48 act as permanently-invalid negs (nc <= 48)
            const float negv = (lane < nc[k]) ? val : -1e30f;
            // invalid pos -> +1e30 -> (mneg - pos_i) <= -1e29 -> relu term exactly 0.0f
            const float posv = (lane >= 48 && (lane - 48) < pc[k]) ? val : 1e30f;
            const float mneg = MARGIN + negv;

            float s = 0.0f;
            #pragma unroll
            for (int i = 0; i < P; ++i) {
                s += fmaxf(mneg - readlane_f(posv, 48 + i), 0.0f);
            }
            tot += s;
            cnt += (float)(pc[k] * nc[k]);               // closed-form pair count
        }
    } else {
        // ---- tail path (never taken for B=32768, kept for generality) ----
        for (int k = 0; k < PROBS_PER_WAVE; ++k) {
            const int b = b0 + k;
            if (b >= B) break;
            const int pc = pos_counts[b];
            const int nc = neg_counts[b];
            float myval  = 0.0f;
            float negval = -1e30f;
            if (lane >= 48) {
                const int idx = pos_indices[(size_t)b * P + (lane - 48)];
                myval = scores[(size_t)b * C + idx];
            } else if (lane < nc) {
                const int idx = neg_indices[(size_t)b * N + lane];
                negval = scores[(size_t)b * C + idx];
            }
            float s = 0.0f;
            for (int i = 0; i < pc; ++i) {
                const float pos_i = __shfl(myval, 48 + i);
                s += fmaxf(MARGIN - pos_i + negval, 0.0f);
            }
            tot += s;
            cnt += (float)(pc * nc);
        }
    }

    // wave reduce total (count is wave-uniform already)
    #pragma unroll
    for (int off = 32; off; off >>= 1) tot += __shfl_xor(tot, off);

    __shared__ float2 lds[WAVES_PER_BLOCK];
    __shared__ int is_last;
    if (lane == 0) lds[wave] = make_float2(tot, cnt);
    __syncthreads();

    if (threadIdx.x == 0) {
        float2 acc = lds[0];
        #pragma unroll
        for (int w = 1; w < WAVES_PER_BLOCK; ++w) { acc.x += lds[w].x; acc.y += lds[w].y; }
        pk64 pk; pk.f = acc;
        // agent-scope release store so the last block (possibly another XCD) sees it
        __hip_atomic_store(&partials[blockIdx.x], pk.u,
                           __ATOMIC_RELEASE, __HIP_MEMORY_SCOPE_AGENT);
        const unsigned old = __hip_atomic_fetch_add(ticket, 1u,
                           __ATOMIC_ACQ_REL, __HIP_MEMORY_SCOPE_AGENT);
        is_last = (old == (unsigned)(gridDim.x - 1)) ? 1 : 0;
    }
    __syncthreads();

    if (is_last) {
        // identical reduce order to the old final kernel -> bit-identical result
        const int n = gridDim.x;
        float T = 0.0f, Cn = 0.0f;
        for (int i = threadIdx.x; i < n; i += BLOCK) {
            pk64 pk;
            pk.u = __hip_atomic_load(&partials[i],
                                     __ATOMIC_RELAXED, __HIP_MEMORY_SCOPE_AGENT);
            T  += pk.f.x;
            Cn += pk.f.y;
        }
        #pragma unroll
        for (int off = 32; off; off >>= 1) {
            T  += __shfl_xor(T, off);
            Cn += __shfl_xor(Cn, off);
        }
        __syncthreads();   // lds[] reuse hazard: everyone done with phase-1 values
        if (lane == 0) lds[wave] = make_float2(T, Cn);
        __syncthreads();
        if (threadIdx.x == 0) {
            float TT = 0.0f, CC = 0.0f;
            #pragma unroll
            for (int w = 0; w < WAVES_PER_BLOCK; ++w) { TT += lds[w].x; CC += lds[w].y; }
            out[0] = (CC > 0.0f) ? (TT / fmaxf(CC, 1.0f)) : 0.0f;
        }
    }
}

extern "C" void kernel_launch(void* const* d_in, const int* in_sizes, int n_in,
                              void* d_out, int out_size, void* d_ws, size_t ws_size,
                              hipStream_t stream) {
    const float* scores      = (const float*)d_in[0];
    const int*   pos_indices = (const int*)d_in[1];
    const int*   neg_indices = (const int*)d_in[2];
    const int*   pos_counts  = (const int*)d_in[3];
    const int*   neg_counts  = (const int*)d_in[4];
    float*       out         = (float*)d_out;

    const int B = in_sizes[3];                       // 32768
    const int grid = (B + PROBS_PER_BLOCK - 1) / PROBS_PER_BLOCK;  // 2048

    // ws layout: [0..3] ticket (zeroed in-stream), [16 ...] packed float2 partials
    unsigned* ticket = (unsigned*)d_ws;
    unsigned long long* partials = (unsigned long long*)((char*)d_ws + 16);

    hipMemsetAsync(ticket, 0, sizeof(unsigned), stream);
    mpcl_fused_kernel<<<grid, BLOCK, 0, stream>>>(
        scores, pos_indices, neg_indices, pos_counts, neg_counts,
        partials, ticket, out, B);
}

// Round 3
// 79.729 us; speedup vs baseline: 1.7114x; 1.7114x over previous
//
#include <hip/hip_runtime.h>

// MultiPositiveContrastiveLoss: B=32768 problems, C=64 candidates, P=16 pos, N=48 neg.
// v4: fused single kernel, contention-fixed.
//   - v3's 2048 same-address acq-rel ticket RMWs serialized at the cross-XCD coherence
//     point (~50 us). v4 uses 512 blocks x 1024 threads (4 "virtual blocks" each, same
//     wave/lane structure -> bit-identical 2048 partial slots) + a TWO-LEVEL ticket
//     (8 group counters on separate cachelines + 1 top counter; max 64 contenders/address).
//   - All atomics RELAXED agent-scope (no per-block L2 writeback/invalidate); ordering via
//     vmcnt(0) drain before barriers + real-time order at the coherence point.
//   - Winner block reduces with the exact thread/stride/shfl/LDS order of the old final
//     kernel (threads < 256, stride 256) -> result bit-identical to v1/v2.

#define MARGIN 0.5f

constexpr int C = 64;
constexpr int P = 16;
constexpr int N = 48;
constexpr int BLOCK = 1024;
constexpr int WAVES_PER_BLOCK = BLOCK / 64;        // 16
constexpr int PROBS_PER_WAVE = 4;
constexpr int VBLK_WAVES = 4;                      // waves per virtual block
constexpr int VBLK_PER_BLOCK = WAVES_PER_BLOCK / VBLK_WAVES;   // 4
constexpr int PROBS_PER_VBLK = VBLK_WAVES * PROBS_PER_WAVE;    // 16
constexpr int PROBS_PER_BLOCK = VBLK_PER_BLOCK * PROBS_PER_VBLK; // 64
constexpr int GROUP = 64;                          // blocks per level-1 ticket

__device__ __forceinline__ float readlane_f(float v, int l) {
    return __uint_as_float(__builtin_amdgcn_readlane(__float_as_uint(v), l));
}

union pk64 { float2 f; unsigned long long u; };

__global__ __launch_bounds__(BLOCK) void mpcl_fused_kernel(
    const float* __restrict__ scores,
    const int*   __restrict__ pos_indices,
    const int*   __restrict__ neg_indices,
    const int*   __restrict__ pos_counts,
    const int*   __restrict__ neg_counts,
    unsigned long long* __restrict__ partials,   // packed float2, one per virtual block
    unsigned*    __restrict__ tickets,           // [g*32] group counters, [ngroups*32] top
    float*       __restrict__ out,
    int B, int nvb)                              // nvb = ceil(B/16) partial slots
{
    const int lane = threadIdx.x & 63;
    const int wave = threadIdx.x >> 6;
    const int vb   = blockIdx.x * VBLK_PER_BLOCK + (wave >> 2);  // virtual block id
    const int vw   = wave & 3;                                    // virtual wave id
    const int b0   = vb * PROBS_PER_VBLK + vw * PROBS_PER_WAVE;

    float tot = 0.0f;
    float cnt = 0.0f;

    if (b0 + PROBS_PER_WAVE <= B) {
        // ---- fast path: batch ALL loads, zero dependency levels between them ----
        int   pc[PROBS_PER_WAVE], nc[PROBS_PER_WAVE], idx[PROBS_PER_WAVE];
        float sc[PROBS_PER_WAVE];
        #pragma unroll
        for (int k = 0; k < PROBS_PER_WAVE; ++k) {
            const int b = b0 + k;
            pc[k] = pos_counts[b];                       // wave-uniform
            nc[k] = neg_counts[b];
            idx[k] = (lane >= 48)
                ? pos_indices[(size_t)b * P + (lane - 48)]
                : neg_indices[(size_t)b * N + lane];     // coalesced per arm
            sc[k] = scores[(size_t)b * C + lane];        // fully coalesced: C == 64
        }

        #pragma unroll
        for (int k = 0; k < PROBS_PER_WAVE; ++k) {
            const float val  = __shfl(sc[k], idx[k]);    // in-wave gather, idx in [0,64)
            const float negv = (lane < nc[k]) ? val : -1e30f;
            const float posv = (lane >= 48 && (lane - 48) < pc[k]) ? val : 1e30f;
            const float mneg = MARGIN + negv;

            float s = 0.0f;
            #pragma unroll
            for (int i = 0; i < P; ++i) {
                s += fmaxf(mneg - readlane_f(posv, 48 + i), 0.0f);
            }
            tot += s;
            cnt += (float)(pc[k] * nc[k]);               // closed-form pair count
        }
    } else {
        // ---- tail path (never taken for B=32768, kept for generality) ----
        for (int k = 0; k < PROBS_PER_WAVE; ++k) {
            const int b = b0 + k;
            if (b >= B) break;
            const int pc = pos_counts[b];
            const int nc = neg_counts[b];
            float myval  = 0.0f;
            float negval = -1e30f;
            if (lane >= 48) {
                const int idx = pos_indices[(size_t)b * P + (lane - 48)];
                myval = scores[(size_t)b * C + idx];
            } else if (lane < nc) {
                const int idx = neg_indices[(size_t)b * N + lane];
                negval = scores[(size_t)b * C + idx];
            }
            float s = 0.0f;
            for (int i = 0; i < pc; ++i) {
                const float pos_i = __shfl(myval, 48 + i);
                s += fmaxf(MARGIN - pos_i + negval, 0.0f);
            }
            tot += s;
            cnt += (float)(pc * nc);
        }
    }

    // wave reduce total (count is wave-uniform already) — identical to v2
    #pragma unroll
    for (int off = 32; off; off >>= 1) tot += __shfl_xor(tot, off);

    __shared__ float2 lds2[WAVES_PER_BLOCK];
    __shared__ int is_last;
    if (lane == 0) lds2[wave] = make_float2(tot, cnt);
    __syncthreads();

    // one thread per virtual block combines its 4 waves in old wave-order, stores slot
    if (lane == 0 && vw == 0) {
        const int wbase = wave;            // wave, wave+1, wave+2, wave+3
        float2 acc = lds2[wbase];
        #pragma unroll
        for (int w = 1; w < VBLK_WAVES; ++w) {
            acc.x += lds2[wbase + w].x;
            acc.y += lds2[wbase + w].y;
        }
        pk64 pk; pk.f = acc;
        __hip_atomic_store(&partials[vb], pk.u,
                           __ATOMIC_RELAXED, __HIP_MEMORY_SCOPE_AGENT);
        asm volatile("s_waitcnt vmcnt(0)" ::: "memory");  // store ack'd at coherence point
    }
    __syncthreads();   // all partial stores of this block drained before ticketing

    if (threadIdx.x == 0) {
        const int g = blockIdx.x / GROUP;
        const unsigned ngroups = (gridDim.x + GROUP - 1) / GROUP;
        const unsigned rem = gridDim.x - (unsigned)(g * GROUP);
        const unsigned gsize = rem < (unsigned)GROUP ? rem : (unsigned)GROUP;
        int last = 0;
        const unsigned o = __hip_atomic_fetch_add(&tickets[g * 32], 1u,
                               __ATOMIC_RELAXED, __HIP_MEMORY_SCOPE_AGENT);
        if (o == gsize - 1) {   // this block completes its group
            const unsigned t = __hip_atomic_fetch_add(&tickets[ngroups * 32], 1u,
                                   __ATOMIC_RELAXED, __HIP_MEMORY_SCOPE_AGENT);
            last = (t == ngroups - 1);
        }
        is_last = last;
    }
    __syncthreads();

    if (is_last) {
        // exact replica of the old 256-thread final kernel (bit-identical order)
        float T = 0.0f, Cn = 0.0f;
        if (threadIdx.x < 256) {
            for (int i = threadIdx.x; i < nvb; i += 256) {
                pk64 pk;
                pk.u = __hip_atomic_load(&partials[i],
                                         __ATOMIC_RELAXED, __HIP_MEMORY_SCOPE_AGENT);
                T  += pk.f.x;
                Cn += pk.f.y;
            }
        }
        #pragma unroll
        for (int off = 32; off; off >>= 1) {
            T  += __shfl_xor(T, off);
            Cn += __shfl_xor(Cn, off);
        }
        __syncthreads();                    // lds2 reuse hazard
        if (lane == 0) lds2[wave] = make_float2(T, Cn);   // waves 4..15 write zeros
        __syncthreads();
        if (threadIdx.x == 0) {
            float TT = 0.0f, CC = 0.0f;
            #pragma unroll
            for (int w = 0; w < 4; ++w) { TT += lds2[w].x; CC += lds2[w].y; }
            out[0] = (CC > 0.0f) ? (TT / fmaxf(CC, 1.0f)) : 0.0f;
        }
    }
}

extern "C" void kernel_launch(void* const* d_in, const int* in_sizes, int n_in,
                              void* d_out, int out_size, void* d_ws, size_t ws_size,
                              hipStream_t stream) {
    const float* scores      = (const float*)d_in[0];
    const int*   pos_indices = (const int*)d_in[1];
    const int*   neg_indices = (const int*)d_in[2];
    const int*   pos_counts  = (const int*)d_in[3];
    const int*   neg_counts  = (const int*)d_in[4];
    float*       out         = (float*)d_out;

    const int B    = in_sizes[3];                              // 32768
    const int grid = (B + PROBS_PER_BLOCK - 1) / PROBS_PER_BLOCK;  // 512
    const int nvb  = (B + PROBS_PER_VBLK - 1) / PROBS_PER_VBLK;    // 2048 partial slots
    const int ngroups = (grid + GROUP - 1) / GROUP;                // 8

    // ws layout: [0 .. (ngroups+1)*128) tickets (one 128B cacheline each, zeroed
    // in-stream), then packed-float2 partials (4 slots per block).
    unsigned* tickets = (unsigned*)d_ws;
    const size_t tick_bytes = (size_t)(ngroups + 1) * 128;
    unsigned long long* partials =
        (unsigned long long*)((char*)d_ws + ((tick_bytes + 255) & ~(size_t)255));

    hipMemsetAsync(tickets, 0, tick_bytes, stream);
    mpcl_fused_kernel<<<grid, BLOCK, 0, stream>>>(
        scores, pos_indices, neg_indices, pos_counts, neg_counts,
        partials, tickets, out, B, nvb);
}

// Round 4
// 75.598 us; speedup vs baseline: 1.8050x; 1.0546x over previous
//
#include <hip/hip_runtime.h>

// MultiPositiveContrastiveLoss: B=32768 problems, C=64 candidates, P=16 pos, N=48 neg.
// v5: two-kernel skeleton (v2, best measured: fusion + tickets were a net LOSS — the
// kernel boundary is the cheapest grid-wide barrier: no atomics, no zero-init, no tail).
// Partial kernel polish vs v2, all bit-order-preserving:
//   - idx load via per-lane pointer select (1 load instr/problem instead of 2 masked arms)
//   - counts via wave-uniform int4 loads (2x s_load_dwordx4 instead of 8 s_load_dword)
//   - scores stay lane-coalesced (C==64), candidate indirection via in-wave ds_bpermute
//   - fixed 16-trip readlane inner loop; invalid pos masked with +1e30 (term == 0.0f)

#define MARGIN 0.5f

constexpr int C = 64;
constexpr int P = 16;
constexpr int N = 48;
constexpr int BLOCK = 256;
constexpr int WAVES_PER_BLOCK = BLOCK / 64;      // 4
constexpr int PROBS_PER_WAVE = 4;
constexpr int PROBS_PER_BLOCK = WAVES_PER_BLOCK * PROBS_PER_WAVE;  // 16

__device__ __forceinline__ float readlane_f(float v, int l) {
    return __uint_as_float(__builtin_amdgcn_readlane(__float_as_uint(v), l));
}

__global__ __launch_bounds__(BLOCK) void mpcl_partial_kernel(
    const float* __restrict__ scores,
    const int*   __restrict__ pos_indices,
    const int*   __restrict__ neg_indices,
    const int*   __restrict__ pos_counts,
    const int*   __restrict__ neg_counts,
    float2*      __restrict__ partials,
    int B)
{
    const int lane = threadIdx.x & 63;
    const int wave = threadIdx.x >> 6;
    const int b0 = (blockIdx.x * WAVES_PER_BLOCK + wave) * PROBS_PER_WAVE;

    float tot = 0.0f;
    float cnt = 0.0f;

    if (b0 + PROBS_PER_WAVE <= B) {
        // ---- fast path: batch ALL loads, zero dependency levels between them ----
        // counts: b0 % 4 == 0 -> 16B-aligned, wave-uniform -> s_load_dwordx4
        const int4 pc4 = *reinterpret_cast<const int4*>(pos_counts + b0);
        const int4 nc4 = *reinterpret_cast<const int4*>(neg_counts + b0);
        const int pc[PROBS_PER_WAVE] = { pc4.x, pc4.y, pc4.z, pc4.w };
        const int nc[PROBS_PER_WAVE] = { nc4.x, nc4.y, nc4.z, nc4.w };

        int   idx[PROBS_PER_WAVE];
        float sc[PROBS_PER_WAVE];
        #pragma unroll
        for (int k = 0; k < PROBS_PER_WAVE; ++k) {
            const int b = b0 + k;
            // one load instruction per problem: per-lane pointer select
            const int* ip = (lane >= 48)
                ? pos_indices + (size_t)b * P + (lane - 48)
                : neg_indices + (size_t)b * N + lane;
            idx[k] = *ip;                                // idx in [0,C)
            sc[k]  = scores[(size_t)b * C + lane];       // fully coalesced: C == 64
        }

        #pragma unroll
        for (int k = 0; k < PROBS_PER_WAVE; ++k) {
            const float val  = __shfl(sc[k], idx[k]);    // in-wave gather (ds_bpermute)
            // lanes >= 48 act as permanently-invalid negs (nc <= 48)
            const float negv = (lane < nc[k]) ? val : -1e30f;
            // invalid pos -> +1e30 -> (mneg - pos_i) <= -1e29 -> relu term exactly 0.0f
            const float posv = (lane >= 48 && (lane - 48) < pc[k]) ? val : 1e30f;
            const float mneg = MARGIN + negv;

            float s = 0.0f;
            #pragma unroll
            for (int i = 0; i < P; ++i) {
                s += fmaxf(mneg - readlane_f(posv, 48 + i), 0.0f);
            }
            tot += s;
            cnt += (float)(pc[k] * nc[k]);               // closed-form pair count
        }
    } else {
        // ---- tail path (never taken for B=32768, kept for generality) ----
        for (int k = 0; k < PROBS_PER_WAVE; ++k) {
            const int b = b0 + k;
            if (b >= B) break;
            const int pc = pos_counts[b];
            const int nc = neg_counts[b];
            float myval  = 0.0f;
            float negval = -1e30f;
            if (lane >= 48) {
                const int idx = pos_indices[(size_t)b * P + (lane - 48)];
                myval = scores[(size_t)b * C + idx];
            } else if (lane < nc) {
                const int idx = neg_indices[(size_t)b * N + lane];
                negval = scores[(size_t)b * C + idx];
            }
            float s = 0.0f;
            for (int i = 0; i < pc; ++i) {
                const float pos_i = __shfl(myval, 48 + i);
                s += fmaxf(MARGIN - pos_i + negval, 0.0f);
            }
            tot += s;
            cnt += (float)(pc * nc);
        }
    }

    // wave reduce total (count is wave-uniform already)
    #pragma unroll
    for (int off = 32; off; off >>= 1) tot += __shfl_xor(tot, off);

    __shared__ float2 lds[WAVES_PER_BLOCK];
    if (lane == 0) lds[wave] = make_float2(tot, cnt);
    __syncthreads();

    if (threadIdx.x == 0) {
        float2 acc = lds[0];
        #pragma unroll
        for (int w = 1; w < WAVES_PER_BLOCK; ++w) { acc.x += lds[w].x; acc.y += lds[w].y; }
        partials[blockIdx.x] = acc;     // plain store; kernel boundary = visibility fence
    }
}

__global__ __launch_bounds__(BLOCK) void mpcl_final_kernel(
    const float2* __restrict__ partials, int n, float* __restrict__ out)
{
    float tot = 0.0f, cnt = 0.0f;
    for (int i = threadIdx.x; i < n; i += BLOCK) {
        const float2 p = partials[i];
        tot += p.x;
        cnt += p.y;
    }
    #pragma unroll
    for (int off = 32; off; off >>= 1) {
        tot += __shfl_xor(tot, off);
        cnt += __shfl_xor(cnt, off);
    }

    __shared__ float2 lds[WAVES_PER_BLOCK];
    const int wave = threadIdx.x >> 6;
    const int lane = threadIdx.x & 63;
    if (lane == 0) lds[wave] = make_float2(tot, cnt);
    __syncthreads();

    if (threadIdx.x == 0) {
        float T = 0.0f, Cn = 0.0f;
        #pragma unroll
        for (int w = 0; w < WAVES_PER_BLOCK; ++w) { T += lds[w].x; Cn += lds[w].y; }
        out[0] = (Cn > 0.0f) ? (T / fmaxf(Cn, 1.0f)) : 0.0f;
    }
}

extern "C" void kernel_launch(void* const* d_in, const int* in_sizes, int n_in,
                              void* d_out, int out_size, void* d_ws, size_t ws_size,
                              hipStream_t stream) {
    const float* scores      = (const float*)d_in[0];
    const int*   pos_indices = (const int*)d_in[1];
    const int*   neg_indices = (const int*)d_in[2];
    const int*   pos_counts  = (const int*)d_in[3];
    const int*   neg_counts  = (const int*)d_in[4];
    float*       out         = (float*)d_out;

    const int B = in_sizes[3];                       // 32768
    const int grid = (B + PROBS_PER_BLOCK - 1) / PROBS_PER_BLOCK;  // 2048

    float2* partials = (float2*)d_ws;                // 2048 * 8 B = 16 KB

    mpcl_partial_kernel<<<grid, BLOCK, 0, stream>>>(
        scores, pos_indices, neg_indices, pos_counts, neg_counts, partials, B);
    mpcl_final_kernel<<<1, BLOCK, 0, stream>>>(partials, grid, out);
}